// Round 1
// 2643.561 us; speedup vs baseline: 1.2492x; 1.2492x over previous
//
#include <hip/hip_runtime.h>
#include <hip/hip_bf16.h>
#include <math.h>

// ---------- types ----------
typedef __bf16 bf16x8 __attribute__((ext_vector_type(8)));
typedef float  f32x4  __attribute__((ext_vector_type(4)));
typedef unsigned short us8 __attribute__((ext_vector_type(8)));
typedef unsigned short us4 __attribute__((ext_vector_type(4)));
typedef unsigned short ush;

__device__ __forceinline__ unsigned short f2bf(float x) {
  unsigned int u = __float_as_uint(x);
  u += 0x7FFFu + ((u >> 16) & 1u);          // RNE
  return (unsigned short)(u >> 16);
}
__device__ __forceinline__ float bf2f(unsigned short v) {
  return __uint_as_float(((unsigned int)v) << 16);
}
// tanh-form GELU: max |diff vs erf-gelu| ~1e-3, harmless vs threshold
__device__ __forceinline__ float gelu_t(float x) {
  float y = 0.7978845608028654f * x * (1.0f + 0.044715f * x * x);
  float e = __expf(2.0f * y);
  return x - x / (e + 1.0f);
}

// Problem constants: B=32, V=4, P=784, D=768; rows n = bp*4+v, bp=b*784+p
// NROW = 100352 = 392*256

// ---------- f32 -> bf16 convert (weights) ----------
__global__ __launch_bounds__(256) void conv_f32_bf16(const float* __restrict__ s,
                                                     unsigned short* __restrict__ d, int n4) {
  int i = blockIdx.x * 256 + threadIdx.x;
  if (i >= n4) return;
  float4 f = ((const float4*)s)[i];
  ushort4 u;
  u.x = f2bf(f.x); u.y = f2bf(f.y); u.z = f2bf(f.z); u.w = f2bf(f.w);
  ((ushort4*)d)[i] = u;
}

// ---------- LayerNorm: read permuted fp32 row, write bf16 row ----------
__global__ __launch_bounds__(256) void ln_kernel(const float* __restrict__ src,
                                                 const float* __restrict__ w,
                                                 const float* __restrict__ b,
                                                 unsigned short* __restrict__ dst) {
  const int wv = threadIdx.x >> 6;
  const int lane = threadIdx.x & 63;
  const int n = blockIdx.x * 4 + wv;            // token row 0..100351
  const int bp = n >> 2, v = n & 3;
  const int bb = bp / 784, p = bp - bb * 784;
  const float* row = src + ((size_t)bb * 3136 + (size_t)v * 784 + p) * 768;
  float4 x0 = ((const float4*)row)[lane];
  float4 x1 = ((const float4*)row)[lane + 64];
  float4 x2 = ((const float4*)row)[lane + 128];
  float s  = x0.x + x0.y + x0.z + x0.w + x1.x + x1.y + x1.z + x1.w
           + x2.x + x2.y + x2.z + x2.w;
  float ss = x0.x*x0.x + x0.y*x0.y + x0.z*x0.z + x0.w*x0.w
           + x1.x*x1.x + x1.y*x1.y + x1.z*x1.z + x1.w*x1.w
           + x2.x*x2.x + x2.y*x2.y + x2.z*x2.z + x2.w*x2.w;
  #pragma unroll
  for (int off = 32; off > 0; off >>= 1) {
    s  += __shfl_xor(s,  off, 64);
    ss += __shfl_xor(ss, off, 64);
  }
  const float mu   = s * (1.0f / 768.0f);
  const float rstd = rsqrtf(ss * (1.0f / 768.0f) - mu * mu + 1e-5f);
  unsigned short* drow = dst + (size_t)n * 768;
  #pragma unroll
  for (int seg = 0; seg < 3; ++seg) {
    float4 xs = (seg == 0) ? x0 : (seg == 1) ? x1 : x2;
    float4 w4 = ((const float4*)w)[lane + seg * 64];
    float4 b4 = ((const float4*)b)[lane + seg * 64];
    ushort4 u;
    u.x = f2bf((xs.x - mu) * rstd * w4.x + b4.x);
    u.y = f2bf((xs.y - mu) * rstd * w4.y + b4.y);
    u.z = f2bf((xs.z - mu) * rstd * w4.z + b4.z);
    u.w = f2bf((xs.w - mu) * rstd * w4.w + b4.w);
    ((ushort4*)drow)[lane + seg * 64] = u;
  }
}

// =====================================================================
// 256x256 tile, BK=64, 8-wave (2M x 4N), 8-phase counted-vmcnt GEMM.
// C = A(M x K) * B(N x K)^T + epilogue. bf16 in, 16x16x32 MFMA.
//
// LDS: 2 buffers x (A 256x64 + B 256x64) bf16 = 128 KiB, XOR-swizzled
// (chunk c of row r stored at chunk c^(r&7); realized by pre-swizzling the
// global source address of global_load_lds, LDS stays linear).
//
// Wave (wm=w>>2, wn=w&3) owns C rows {wm*64 + hm*128 + mi4*16 + ...} and
// cols {wn*32 + hn*128 + ni2*16 + ...}; so phase (hm,hn) reads exactly one
// contiguous 128-row half of A and of B -> rolling half-tile overwrite.
//
// Phase schedule per K-tile t (buf bt = t&1), stage stream H = p+6:
//   q0: read A(hm0)+B(hn0); stage A1(t+1);  bar; MFMA; vmcnt(6); bar
//   q1: read B(hn1);        stage B1(t+1);  bar; MFMA;           bar
//   q2: read A(hm1);        stage A0(t+2);  bar; MFMA;           bar
//   q3: (reuse B frags);    stage B0(t+2);  bar; MFMA; vmcnt(8); bar
// Every region has >=2 barrier-separated phases between its last ds_read
// (completed before that phase's MFMA) and its overwriting stage issue.
// vmcnt(8) guarantees next tile's A0,B0 landed; vmcnt(6) its B1 (and A1,
// which is older). Tail: vmcnt 4 -> 0; prologue stages 6 half-tiles.
// =====================================================================

#define BARX() do { asm volatile("" ::: "memory"); \
                    __builtin_amdgcn_s_barrier();  \
                    asm volatile("" ::: "memory"); } while (0)
#define WAITVM(N) asm volatile("s_waitcnt vmcnt(" #N ")" ::: "memory")

// stage one 128-row half (16 KiB) of A (ISB=0) or B (ISB=1) of K-tile TT
#define STAGE(ISB, HALF, TT) do {                                             \
  const ush* _g = (ISB) ? gB : gA;                                            \
  const int _l0 = (((TT) & 1) << 15) + ((ISB) ? 16384 : 0) + ((HALF) << 13)   \
                + (w << 9);                                                   \
  const size_t _go = (size_t)(((HALF) << 7) + (w << 3)) * K                   \
                   + ((size_t)(TT) << 6);                                     \
  __builtin_amdgcn_global_load_lds(                                           \
      (const __attribute__((address_space(1))) void*)(_g + _go),              \
      (__attribute__((address_space(3))) void*)(smem + _l0), 16, 0, 0);       \
  __builtin_amdgcn_global_load_lds(                                           \
      (const __attribute__((address_space(1))) void*)(_g + _go + ((size_t)K << 6)), \
      (__attribute__((address_space(3))) void*)(smem + _l0 + 4096), 16, 0, 0);\
} while (0)

#define LDA(HM) do {                                                          \
  _Pragma("unroll")                                                           \
  for (int mi4 = 0; mi4 < 4; ++mi4) {                                         \
    const int m = wm * 64 + (HM) * 128 + mi4 * 16 + l16;                      \
    _Pragma("unroll")                                                         \
    for (int kk = 0; kk < 2; ++kk) {                                          \
      const int q = kk * 4 + quad;                                            \
      af[mi4][kk] = *(const bf16x8*)(smem + aofs + m * 64 + ((q ^ l7) << 3)); \
    }                                                                         \
  }                                                                           \
} while (0)

#define LDB(HN, BF) do {                                                      \
  _Pragma("unroll")                                                           \
  for (int ni2 = 0; ni2 < 2; ++ni2) {                                         \
    const int n = wn * 32 + (HN) * 128 + ni2 * 16 + l16;                      \
    _Pragma("unroll")                                                         \
    for (int kk = 0; kk < 2; ++kk) {                                          \
      const int q = kk * 4 + quad;                                            \
      BF[ni2][kk] = *(const bf16x8*)(smem + bofs + n * 64 + ((q ^ l7) << 3)); \
    }                                                                         \
  }                                                                           \
} while (0)

#define MFMAC(HM, HN, BF) do {                                                \
  __builtin_amdgcn_s_setprio(1);                                              \
  _Pragma("unroll")                                                           \
  for (int mi4 = 0; mi4 < 4; ++mi4)                                           \
    _Pragma("unroll")                                                         \
    for (int ni2 = 0; ni2 < 2; ++ni2)                                         \
      _Pragma("unroll")                                                       \
      for (int kk = 0; kk < 2; ++kk)                                          \
        acc[(HM)*4 + mi4][(HN)*2 + ni2] = __builtin_amdgcn_mfma_f32_16x16x32_bf16( \
            af[mi4][kk], BF[ni2][kk], acc[(HM)*4 + mi4][(HN)*2 + ni2], 0, 0, 0); \
  __builtin_amdgcn_s_setprio(0);                                              \
} while (0)

// EPI: 0 = +bias -> qkv bf16 [bp][seg][h][v][96]
//      1/3 = +bias +aux residual -> fp32 (unfolded addr)
//      2 = +bias, gelu -> bf16 row-major (N cols)
template <int K, int EPI>
__global__ __launch_bounds__(512, 2) void gemm256(const ush* __restrict__ A,
                                                  const ush* __restrict__ Bm,
                                                  const float* __restrict__ bias,
                                                  void* __restrict__ outp,
                                                  const float* __restrict__ aux,
                                                  int N) {
  __shared__ __attribute__((aligned(16))) ush smem[65536];   // 128 KiB
  constexpr int NT = K / 64;
  const int tid  = threadIdx.x;
  const int w    = tid >> 6;
  const int lane = tid & 63;
  const int quad = lane >> 4;
  const int l16  = lane & 15;
  const int l7   = l16 & 7;
  const int wm   = w >> 2;        // 0..1
  const int wn   = w & 3;         // 0..3

  // XCD-aware bijective remap: each XCD owns nwg/8 consecutive (by,bx) in
  // bx-fastest order -> A row-panel reused across all bx within one L2.
  const int gx   = gridDim.x;
  const int nwg  = gx * 392;
  const int flat = blockIdx.y * gx + blockIdx.x;
  const int xcd  = flat & 7;
  const int pos  = xcd * (nwg >> 3) + (flat >> 3);
  const int by   = pos / gx;
  const int bx   = pos - by * gx;

  // pre-swizzled per-lane global source (chunk cb loads global chunk cb^r8)
  const int r8  = lane >> 3;
  const int cb  = lane & 7;
  const int swo = (cb ^ r8) << 3;
  const ush* gA = A  + (size_t)(by * 256 + r8) * K + swo;
  const ush* gB = Bm + (size_t)(bx * 256 + r8) * K + swo;

  f32x4 acc[8][4];
  #pragma unroll
  for (int i = 0; i < 8; ++i)
    #pragma unroll
    for (int j = 0; j < 4; ++j) {
      f32x4 z = {0.0f, 0.0f, 0.0f, 0.0f};
      acc[i][j] = z;
    }
  bf16x8 af[4][2], bf0[2][2], bf1[2][2];

  // ---- prologue: stage half-tiles H=0..5 = A0,B0,A1,B1(0), A0,B0(1) ----
  STAGE(0, 0, 0); STAGE(1, 0, 0); STAGE(0, 1, 0);
  STAGE(1, 1, 0); STAGE(0, 0, 1); STAGE(1, 0, 1);
  WAITVM(8);              // A0(0),B0(0) landed (4 newest halves may fly)
  BARX();

  #pragma unroll 2
  for (int t = 0; t < NT; ++t) {
    const int aofs = (t & 1) << 15;
    const int bofs = aofs + 16384;
    // ---- q0: hm=0, hn=0 ----
    LDA(0); LDB(0, bf0);
    if (t <= NT - 2) STAGE(0, 1, t + 1);     // A1(t+1) -> other buf
    BARX();
    MFMAC(0, 0, bf0);
    if (t < NT - 1) { WAITVM(6); } else { WAITVM(0); }  // B1(t) (and A1(t)) landed
    BARX();
    // ---- q1: hm=0, hn=1 ----
    LDB(1, bf1);
    if (t <= NT - 2) STAGE(1, 1, t + 1);     // B1(t+1) -> other buf
    BARX();
    MFMAC(0, 1, bf1);
    BARX();
    // ---- q2: hm=1, hn=0 ----
    LDA(1);
    if (t <= NT - 3) STAGE(0, 0, t + 2);     // A0(t+2) -> this buf (half0 free)
    BARX();
    MFMAC(1, 0, bf0);
    BARX();
    // ---- q3: hm=1, hn=1 (B frags reused, no ds_reads) ----
    if (t <= NT - 3) STAGE(1, 0, t + 2);     // B0(t+2) -> this buf (half0 free)
    BARX();
    MFMAC(1, 1, bf1);
    if (t <= NT - 3)      { WAITVM(8); }     // A0,B0(t+1) landed
    else if (t == NT - 2) { WAITVM(4); }
    BARX();
  }

  // ---- epilogue: 4 stages of 64 rows x 256 cols via LDS (stride 260) ----
  float* lsm = (float*)smem;
  #pragma unroll
  for (int s = 0; s < 4; ++s) {
    if (wm == (s & 1)) {
      const int hm = s >> 1;                 // compile-time (s unrolled)
      #pragma unroll
      for (int mi4 = 0; mi4 < 4; ++mi4)
        #pragma unroll
        for (int ni = 0; ni < 4; ++ni) {
          const int col = wn * 32 + (ni >> 1) * 128 + (ni & 1) * 16 + l16;
          #pragma unroll
          for (int r = 0; r < 4; ++r) {
            const int row_l = mi4 * 16 + quad * 4 + r;
            lsm[row_l * 260 + col] = acc[hm * 4 + mi4][ni][r];
          }
        }
    }
    __syncthreads();
    #pragma unroll
    for (int j = 0; j < 8; ++j) {
      const int cc    = tid + 512 * j;       // 0..4095 = 64 rows x 64 chunks
      const int row_l = cc >> 6;
      const int c4    = (cc & 63) << 2;
      f32x4 vv = *(const f32x4*)&lsm[row_l * 260 + c4];
      const int rr    = by * 256 + s * 64 + row_l;
      const int col_g = bx * 256 + c4;
      f32x4 b4 = *(const f32x4*)&bias[col_g];
      vv += b4;
      if (EPI == 0) {
        const int seg = col_g / 768;
        const int c2  = col_g - seg * 768;
        const int hh  = c2 / 96;
        const int dd  = c2 - hh * 96;
        const int bp = rr >> 2, v = rr & 3;
        us4 u = { f2bf(vv[0]), f2bf(vv[1]), f2bf(vv[2]), f2bf(vv[3]) };
        *(us4*)((unsigned short*)outp + (size_t)bp * 9216 + seg * 3072 + hh * 384 + v * 96 + dd) = u;
      } else if (EPI == 1 || EPI == 3) {
        const int bp = rr >> 2, v = rr & 3;
        const int bb = bp / 784, p = bp - bb * 784;
        const size_t addr = ((size_t)bb * 3136 + (size_t)v * 784 + p) * 768 + col_g;
        f32x4 a4 = *(const f32x4*)(aux + addr);
        vv += a4;
        *(f32x4*)((float*)outp + addr) = vv;
      } else { // EPI == 2: gelu -> bf16 row-major
        us4 u = { f2bf(gelu_t(vv[0])), f2bf(gelu_t(vv[1])),
                  f2bf(gelu_t(vv[2])), f2bf(gelu_t(vv[3])) };
        *(us4*)((unsigned short*)outp + (size_t)rr * N + col_g) = u;
      }
    }
    __syncthreads();
  }
}

// ---------- tiny cross-view attention: one thread per (bp, head, vq) ----------
__global__ __launch_bounds__(256) void attn_kernel(const unsigned short* __restrict__ qs,
                                                   unsigned short* __restrict__ o) {
  int idx = blockIdx.x * 256 + threadIdx.x;   // 25088*32 total
  int vq = idx & 3;
  int h  = (idx >> 2) & 7;
  int bp = idx >> 5;
  const unsigned short* qp = qs + (size_t)bp * 9216 + h * 384 + vq * 96;
  const unsigned short* kp = qs + (size_t)bp * 9216 + 3072 + h * 384;
  const unsigned short* vp = qs + (size_t)bp * 9216 + 6144 + h * 384;
  float s0 = 0.f, s1 = 0.f, s2 = 0.f, s3 = 0.f;
  #pragma unroll
  for (int c = 0; c < 96; c += 8) {
    us8 q8 = *(const us8*)(qp + c);
    us8 k0 = *(const us8*)(kp + c);
    us8 k1 = *(const us8*)(kp + 96 + c);
    us8 k2 = *(const us8*)(kp + 192 + c);
    us8 k3 = *(const us8*)(kp + 288 + c);
    #pragma unroll
    for (int j = 0; j < 8; ++j) {
      float qf = bf2f(q8[j]);
      s0 += qf * bf2f(k0[j]);
      s1 += qf * bf2f(k1[j]);
      s2 += qf * bf2f(k2[j]);
      s3 += qf * bf2f(k3[j]);
    }
  }
  const float scale = 0.10206207261596575f;  // 1/sqrt(96)
  s0 *= scale; s1 *= scale; s2 *= scale; s3 *= scale;
  float m = fmaxf(fmaxf(s0, s1), fmaxf(s2, s3));
  float e0 = __expf(s0 - m), e1 = __expf(s1 - m), e2 = __expf(s2 - m), e3 = __expf(s3 - m);
  float inv = 1.0f / (e0 + e1 + e2 + e3);
  e0 *= inv; e1 *= inv; e2 *= inv; e3 *= inv;
  unsigned short* op = o + (size_t)(bp * 4 + vq) * 768 + h * 96;
  #pragma unroll
  for (int c = 0; c < 96; c += 8) {
    us8 v0 = *(const us8*)(vp + c);
    us8 v1 = *(const us8*)(vp + 96 + c);
    us8 v2 = *(const us8*)(vp + 192 + c);
    us8 v3 = *(const us8*)(vp + 288 + c);
    us8 r;
    #pragma unroll
    for (int j = 0; j < 8; ++j) {
      float val = e0 * bf2f(v0[j]) + e1 * bf2f(v1[j]) + e2 * bf2f(v2[j]) + e3 * bf2f(v3[j]);
      r[j] = f2bf(val);
    }
    *(us8*)(op + c) = r;
  }
}

// ---------- launch ----------
extern "C" void kernel_launch(void* const* d_in, const int* in_sizes, int n_in,
                              void* d_out, int out_size, void* d_ws, size_t ws_size,
                              hipStream_t stream) {
  const float* x         = (const float*)d_in[0];
  const float* norm1_w   = (const float*)d_in[2];
  const float* norm1_b   = (const float*)d_in[3];
  const float* in_proj_w = (const float*)d_in[4];
  const float* in_proj_b = (const float*)d_in[5];
  const float* out_w     = (const float*)d_in[6];
  const float* out_b     = (const float*)d_in[7];
  const float* norm2_w   = (const float*)d_in[8];
  const float* norm2_b   = (const float*)d_in[9];
  const float* ffn_w1    = (const float*)d_in[10];
  const float* ffn_b1    = (const float*)d_in[11];
  const float* ffn_w2    = (const float*)d_in[12];
  const float* ffn_b2    = (const float*)d_in[13];
  float* out = (float*)d_out;

  char* ws = (char*)d_ws;
  unsigned short* wq = (unsigned short*)ws;                           // 616.6 MB
  unsigned short* wh = (unsigned short*)(ws + 616562688u);            // 154.1 MB
  unsigned short* wB = (unsigned short*)(ws + 616562688u + 154140672u);
  unsigned short* wIn  = wB;
  unsigned short* wOut = wB + 1769472;
  unsigned short* wF1  = wOut + 589824;
  unsigned short* wF2  = wF1 + 2359296;

  conv_f32_bf16<<<(442368 + 255) / 256, 256, 0, stream>>>(in_proj_w, wIn, 442368);
  conv_f32_bf16<<<(147456 + 255) / 256, 256, 0, stream>>>(out_w, wOut, 147456);
  conv_f32_bf16<<<(589824 + 255) / 256, 256, 0, stream>>>(ffn_w1, wF1, 589824);
  conv_f32_bf16<<<(589824 + 255) / 256, 256, 0, stream>>>(ffn_w2, wF2, 589824);

  // LN1: x (permuted read) -> wh
  ln_kernel<<<25088, 256, 0, stream>>>(x, norm1_w, norm1_b, wh);
  // QKV: wh(100352x768) @ in_proj_w^T -> wq (attention layout)
  gemm256<768, 0><<<dim3(9, 392), 512, 0, stream>>>(wh, wIn, in_proj_b, (void*)wq, nullptr, 2304);
  // attention: wq -> wh (o, bf16 rows)
  attn_kernel<<<3136, 256, 0, stream>>>(wq, wh);
  // out-proj + residual(x): wh @ out_w^T -> d_out fp32 (unfolded)
  gemm256<768, 1><<<dim3(3, 392), 512, 0, stream>>>(wh, wOut, out_b, (void*)out, x, 768);
  // LN2: d_out (permuted read) -> wh
  ln_kernel<<<25088, 256, 0, stream>>>(out, norm2_w, norm2_b, wh);
  // FFN1 + gelu: wh @ ffn_w1^T -> wq bf16 row-major
  gemm256<768, 2><<<dim3(12, 392), 512, 0, stream>>>(wh, wF1, ffn_b1, (void*)wq, nullptr, 3072);
  // FFN2 + residual(d_out): wq(100352x3072) @ ffn_w2^T -> d_out fp32
  gemm256<3072, 3><<<dim3(3, 392), 512, 0, stream>>>(wq, wF2, ffn_b2, (void*)out, out, 768);

  (void)in_sizes; (void)n_in; (void)out_size; (void)ws_size;
}